// Round 1
// baseline (96.418 us; speedup 1.0000x reference)
//
#include <hip/hip_runtime.h>
#include <hip/hip_bf16.h>
#include <stdint.h>

// Problem constants: B=4, C=256, H=W=64 -> L=4096, POS=16384
// n_mem=64, sqrt_fin=16, NQ=NK=1024 projection outputs, scale=1/4.
using bf16 = __hip_bfloat16;
typedef __attribute__((ext_vector_type(8))) short bf16x8;
typedef __attribute__((ext_vector_type(4))) float f32x4;

#define POS 16384
#define CDIM 256
#define LDIM 4096

// ---------- prep: fp32 -> bf16 cast ----------
__global__ void cast_bf16_kernel(const float* __restrict__ in, bf16* __restrict__ out, int n) {
    int i = blockIdx.x * blockDim.x + threadIdx.x;
    int stride = gridDim.x * blockDim.x;
    for (; i < n; i += stride) out[i] = __float2bfloat16(in[i]);
}

// ---------- prep: x [B,C,L] f32 -> Xt [B*L, C] bf16 (transpose+cast) ----------
__global__ void transpose_cast_kernel(const float* __restrict__ x, bf16* __restrict__ xt) {
    __shared__ float tile[64][65];
    int l0 = blockIdx.x * 64, c0 = blockIdx.y * 64, b = blockIdx.z;
    const float* xb = x + ((size_t)b * CDIM + c0) * LDIM + l0;
    for (int k = 0; k < 16; k++) {
        int idx = threadIdx.x + k * 256;
        int c = idx >> 6, l = idx & 63;
        tile[c][l] = xb[(size_t)c * LDIM + l];
    }
    __syncthreads();
    bf16* xo = xt + ((size_t)b * LDIM + l0) * CDIM + c0;
    for (int k = 0; k < 16; k++) {
        int idx = threadIdx.x + k * 256;
        int l = idx >> 6, c = idx & 63;
        xo[(size_t)l * CDIM + c] = __float2bfloat16(tile[c][l]);
    }
}

// ---------- prep: Mmat[n][o] = sum_c v[n][c]*Wo[o][c]  (64 x 256, f32) ----------
__global__ void mmat_kernel(const float* __restrict__ v, const float* __restrict__ wo,
                            float* __restrict__ mmat) {
    int o = blockIdx.x, n = threadIdx.x;  // grid 256, block 64
    const float* vr = v + n * CDIM;
    const float* wr = wo + o * CDIM;
    float acc = 0.f;
    for (int c = 0; c < CDIM; c++) acc += vr[c] * wr[c];
    mmat[n * CDIM + o] = acc;
}

// ---------- main projection GEMM: 128x128 tile, K=256 in 8 steps of 32 ----------
// KPART=0: q-projection -> qsum (scaled) via global atomics
// KPART=1: k-projection (permuted B columns) -> pooled via global atomics
template<int KPART>
__global__ __launch_bounds__(256) void gemm_proj_kernel(
    const bf16* __restrict__ Xt,    // [POS, 256]
    const bf16* __restrict__ Wb,    // [1024, 256]
    const float* __restrict__ bias, // [1024]
    float* __restrict__ qsumG,      // [POS, 16]
    float* __restrict__ pooledG)    // [POS, 64]
{
    __shared__ __align__(16) bf16 As[128 * 32];
    __shared__ __align__(16) bf16 Bs[128 * 32];
    __shared__ float qsLDS[128 * 16];  // only used by KPART=1

    const int t = threadIdx.x;
    const int bx = blockIdx.x;   // M tile (positions)
    const int by = blockIdx.y;   // N tile (outputs)
    const int l0 = bx * 128;
    const int o0 = by * 128;
    const int lane = t & 63;
    const int w = t >> 6;
    const int wm = w >> 1, wn = w & 1;
    const int s = lane & 15, g = lane >> 4;

    f32x4 acc[4][4] = {};

    const int cid0 = t, cid1 = t + 256;
    // B-side source row (permuted columns for k-part so s lives in (wn,nf,lane_bit3))
    int r0, r1;
    if (KPART) {
        int rp0 = cid0 >> 2, rp1 = cid1 >> 2;
        r0 = (rp0 & 7) * 16 + ((rp0 >> 4) << 1) + ((rp0 >> 3) & 1);
        r1 = (rp1 & 7) * 16 + ((rp1 >> 4) << 1) + ((rp1 >> 3) & 1);
    } else { r0 = cid0 >> 2; r1 = cid1 >> 2; }

    for (int kt = 0; kt < 8; kt++) {
        const char* xb  = (const char*)Xt + (size_t)l0 * 512 + kt * 64;
        const char* wbp = (const char*)Wb + (size_t)o0 * 512 + kt * 64;
        uint4 a0 = *(const uint4*)(xb + (size_t)(cid0 >> 2) * 512 + (cid0 & 3) * 16);
        uint4 a1 = *(const uint4*)(xb + (size_t)(cid1 >> 2) * 512 + (cid1 & 3) * 16);
        uint4 b0 = *(const uint4*)(wbp + (size_t)r0 * 512 + (cid0 & 3) * 16);
        uint4 b1 = *(const uint4*)(wbp + (size_t)r1 * 512 + (cid1 & 3) * 16);
        __syncthreads();  // protect previous iteration's fragment reads
        *(uint4*)((char*)As + (size_t)cid0 * 16) = a0;
        *(uint4*)((char*)As + (size_t)cid1 * 16) = a1;
        *(uint4*)((char*)Bs + (size_t)cid0 * 16) = b0;
        *(uint4*)((char*)Bs + (size_t)cid1 * 16) = b1;
        __syncthreads();

        bf16x8 af[4], bfr[4];
#pragma unroll
        for (int mf = 0; mf < 4; mf++)
            af[mf] = *(const bf16x8*)((const char*)As + (size_t)((wm * 64 + mf * 16 + s) * 32 + g * 8) * 2);
#pragma unroll
        for (int nf = 0; nf < 4; nf++)
            bfr[nf] = *(const bf16x8*)((const char*)Bs + (size_t)((wn * 64 + nf * 16 + s) * 32 + g * 8) * 2);
#pragma unroll
        for (int mf = 0; mf < 4; mf++)
#pragma unroll
            for (int nf = 0; nf < 4; nf++)
                acc[mf][nf] = __builtin_amdgcn_mfma_f32_16x16x32_bf16(af[mf], bfr[nf], acc[mf][nf], 0, 0, 0);
    }

    // C/D mapping (m89-verified): col = lane&15, row = (lane>>4)*4 + reg
    if (!KPART) {
        // q epilogue: qsum[pos][s] += (scale/64) * sum_m relu(xq + bq)
        float bqv[4];
#pragma unroll
        for (int nf = 0; nf < 4; nf++) bqv[nf] = bias[o0 + wn * 64 + nf * 16 + s];
        const float cscale = 0.25f / 64.0f;
#pragma unroll
        for (int mf = 0; mf < 4; mf++) {
#pragma unroll
            for (int r = 0; r < 4; r++) {
                float qp = 0.f;
#pragma unroll
                for (int nf = 0; nf < 4; nf++)
                    qp += fmaxf(acc[mf][nf][r] + bqv[nf], 0.f);
                int pos = l0 + wm * 64 + mf * 16 + g * 4 + r;
                atomicAdd(&qsumG[pos * 16 + s], qp * cscale);
            }
        }
    } else {
        // k epilogue: pooled[pos][n] += sum_s qsum[pos][s] * relu(xk + bk)
#pragma unroll
        for (int j = 0; j < 8; j++) {
            int idx = t + j * 256;  // 0..2047 = 128 pos x 16 s
            qsLDS[idx] = qsumG[(l0 + (idx >> 4)) * 16 + (idx & 15)];
        }
        __syncthreads();
        const int n_l = lane & 7;
        const int sb0 = (lane >> 3) & 1;
        float bkv[4]; int sv[4];
#pragma unroll
        for (int nf = 0; nf < 4; nf++) {
            sv[nf] = ((wn * 4 + nf) << 1) + sb0;
            bkv[nf] = bias[o0 + n_l * 16 + sv[nf]];
        }
#pragma unroll
        for (int mf = 0; mf < 4; mf++) {
#pragma unroll
            for (int r = 0; r < 4; r++) {
                int pos_l = wm * 64 + mf * 16 + g * 4 + r;
                float part = 0.f;
#pragma unroll
                for (int nf = 0; nf < 4; nf++) {
                    float kr = fmaxf(acc[mf][nf][r] + bkv[nf], 0.f);
                    part += qsLDS[pos_l * 16 + sv[nf]] * kr;
                }
                part += __shfl_xor(part, 8);  // fold s bit0 partner
                if (!(lane & 8))
                    atomicAdd(&pooledG[(size_t)(l0 + pos_l) * 64 + (by * 8 + n_l)], part);
            }
        }
    }
}

// ---------- out: x + pooled @ Mmat + bo  (fp32) ----------
__global__ __launch_bounds__(256) void out_kernel(
    const float* __restrict__ x, const float* __restrict__ pooledG,
    const float* __restrict__ mmat, const float* __restrict__ bo,
    float* __restrict__ out)
{
    __shared__ float pl[32 * 64];
    int t = threadIdx.x;           // t = output channel o2
    int P0 = blockIdx.x * 32;      // 32 positions per block
#pragma unroll
    for (int j = 0; j < 8; j++) {
        int idx = t + j * 256;
        pl[idx] = pooledG[(size_t)P0 * 64 + idx];
    }
    float mreg[64];
#pragma unroll
    for (int n = 0; n < 64; n++) mreg[n] = mmat[n * CDIM + t];
    float bov = bo[t];
    __syncthreads();
    int b = P0 >> 12;
    int l0 = P0 & (LDIM - 1);
    const float* xr = x + ((size_t)b * CDIM + t) * LDIM + l0;
    float* orow = out + ((size_t)b * CDIM + t) * LDIM + l0;
    for (int p4 = 0; p4 < 8; p4++) {
        float4 xv = *(const float4*)(xr + p4 * 4);
        float a[4];
#pragma unroll
        for (int q = 0; q < 4; q++) {
            int p = p4 * 4 + q;
            float accv = bov;
#pragma unroll
            for (int n = 0; n < 64; n++) accv += pl[p * 64 + n] * mreg[n];
            a[q] = accv;
        }
        float4 ov = make_float4(xv.x + a[0], xv.y + a[1], xv.z + a[2], xv.w + a[3]);
        *(float4*)(orow + p4 * 4) = ov;
    }
}

extern "C" void kernel_launch(void* const* d_in, const int* in_sizes, int n_in,
                              void* d_out, int out_size, void* d_ws, size_t ws_size,
                              hipStream_t stream) {
    (void)in_sizes; (void)n_in; (void)out_size; (void)ws_size;
    const float* x  = (const float*)d_in[0];
    const float* Wq = (const float*)d_in[1];
    const float* bq = (const float*)d_in[2];
    const float* Wk = (const float*)d_in[3];
    const float* bk = (const float*)d_in[4];
    const float* v  = (const float*)d_in[5];
    const float* Wo = (const float*)d_in[6];
    const float* bo = (const float*)d_in[7];
    float* out = (float*)d_out;

    char* ws = (char*)d_ws;
    bf16*  Xt      = (bf16*)ws;                    // 16384*256*2 = 8,388,608
    bf16*  Wqb     = (bf16*)(ws + 8388608);        // 524,288
    bf16*  Wkb     = (bf16*)(ws + 8912896);        // 524,288
    float* Mm      = (float*)(ws + 9437184);       // 65,536
    float* qsumG   = (float*)(ws + 9502720);       // 1,048,576
    float* pooledG = (float*)(ws + 10551296);      // 4,194,304  (ws end: 14,745,600)

    hipMemsetAsync(qsumG, 0, 1048576 + 4194304, stream);  // qsum + pooled
    cast_bf16_kernel<<<512, 256, 0, stream>>>(Wq, Wqb, 1024 * 256);
    cast_bf16_kernel<<<512, 256, 0, stream>>>(Wk, Wkb, 1024 * 256);
    transpose_cast_kernel<<<dim3(64, 4, 4), 256, 0, stream>>>(x, Xt);
    mmat_kernel<<<256, 64, 0, stream>>>(v, Wo, Mm);
    gemm_proj_kernel<0><<<dim3(128, 8), 256, 0, stream>>>(Xt, Wqb, bq, qsumG, pooledG);
    gemm_proj_kernel<1><<<dim3(128, 8), 256, 0, stream>>>(Xt, Wkb, bk, qsumG, pooledG);
    out_kernel<<<512, 256, 0, stream>>>(x, pooledG, Mm, bo, out);
}

// Round 2
// 41.880 us; speedup vs baseline: 2.3022x; 2.3022x over previous
//
#include <hip/hip_runtime.h>
#include <hip/hip_bf16.h>
#include <stdint.h>

// B=4, C=256, H=W=64 -> L=4096, POS=16384; n_mem=64, sqrt_fin=16, scale=1/4.
using bf16 = __hip_bfloat16;
typedef __attribute__((ext_vector_type(8))) short bf16x8;
typedef __attribute__((ext_vector_type(4))) float f32x4;

#define POS 16384
#define CDIM 256
#define LDIM 4096

// LDS map (128 KiB total)
#define R_OFF(i) ((i) * 32768)      // 3 x 32 KB rotating stage buffers
#define QSW_OFF 98304               // qsumW [64 pos][16 s][8 w] bf16 = 16 KB
#define POOL_OFF 114688             // pooledB [64 pos][64 n] bf16 = 8 KB
#define BQ_OFF 122880               // bq f32[1024]
#define BK_OFF 126976               // bk f32[1024]

__device__ __forceinline__ void gload16(void* lds, const void* g) {
  auto* l3 = (__attribute__((address_space(3))) char*)(uintptr_t)lds;
  auto* g1 = (const __attribute__((address_space(1))) char*)(uintptr_t)g;
  __builtin_amdgcn_global_load_lds((const __attribute__((address_space(1))) void*)g1,
                                   (__attribute__((address_space(3))) void*)l3, 16, 0, 0);
}

template <int CTRL>
__device__ __forceinline__ float dpp_add(float v) {
  int p = __builtin_amdgcn_update_dpp(0, __float_as_int(v), CTRL, 0xf, 0xf, true);
  return v + __int_as_float(p);
}

__device__ __forceinline__ float b2f(short h) {
  return __uint_as_float(((uint32_t)(uint16_t)h) << 16);
}

// ---------- prep: weight casts + MmB[o][n] = bf16(sum_c v[n][c]*Wo[o][c]) ----------
__global__ void prep_kernel(const float* __restrict__ Wq, const float* __restrict__ Wk,
                            const float* __restrict__ v, const float* __restrict__ Wo,
                            bf16* __restrict__ Wqb, bf16* __restrict__ Wkb,
                            bf16* __restrict__ MmBg) {
  int bid = blockIdx.x, t = threadIdx.x;
  if (bid < 512) {
    const float* src = (bid < 256) ? Wq : Wk;
    bf16* dst = (bid < 256) ? Wqb : Wkb;
    int base = (bid & 255) * 1024 + t * 4;
    float4 f = *(const float4*)(src + base);
    dst[base + 0] = __float2bfloat16(f.x);
    dst[base + 1] = __float2bfloat16(f.y);
    dst[base + 2] = __float2bfloat16(f.z);
    dst[base + 3] = __float2bfloat16(f.w);
  } else {
    __shared__ float red[256];
    int o = bid - 512;
    int n = t >> 2, cg = t & 3;
    const float* vr = v + n * CDIM + cg * 64;
    const float* wr = Wo + o * CDIM + cg * 64;
    float a = 0.f;
    for (int c = 0; c < 64; c++) a += vr[c] * wr[c];
    red[t] = a;
    __syncthreads();
    if (t < 64)
      MmBg[o * 64 + t] =
          __float2bfloat16(red[t * 4] + red[t * 4 + 1] + red[t * 4 + 2] + red[t * 4 + 3]);
  }
}

// ---------- x [B,C,L] f32 -> Xt [B*L, C] bf16 ----------
__global__ void transpose_cast_kernel(const float* __restrict__ x, bf16* __restrict__ xt) {
  __shared__ float tile[64][65];
  int l0 = blockIdx.x * 64, c0 = blockIdx.y * 64, b = blockIdx.z;
  const float* xb = x + ((size_t)b * CDIM + c0) * LDIM + l0;
  for (int k = 0; k < 16; k++) {
    int idx = threadIdx.x + k * 256;
    int c = idx >> 6, l = idx & 63;
    tile[c][l] = xb[(size_t)c * LDIM + l];
  }
  __syncthreads();
  bf16* xo = xt + ((size_t)b * LDIM + l0) * CDIM + c0;
  for (int k = 0; k < 16; k++) {
    int idx = threadIdx.x + k * 256;
    int l = idx >> 6, c = idx & 63;
    xo[(size_t)l * CDIM + c] = __float2bfloat16(tile[c][l]);
  }
}

// One K-half phase: wait(vmcnt 4) -> barrier -> issue stage(PP+2) -> 4kt x {ds_read B, 4 MFMA}
#define PHASE(PPX, H)                                                                     \
  {                                                                                       \
    const int pp_ = (PPX);                                                                \
    asm volatile("s_waitcnt vmcnt(4) lgkmcnt(0)" ::: "memory");                           \
    __builtin_amdgcn_s_barrier();                                                         \
    __builtin_amdgcn_sched_barrier(0);                                                    \
    const int sp_ = pp_ + 2;                                                              \
    if (sp_ < 32) {                                                                       \
      const bf16* Wsrc_ = (sp_ < 16) ? Wqb : Wkb;                                         \
      const int so0_ = ((sp_ >> 1) & 7) * 128;                                            \
      const int sh_ = sp_ & 1;                                                            \
      char* dst_ = smem + R_OFF(sp_ % 3);                                                 \
      const char* srcb_ = (const char*)Wsrc_ + (size_t)so0_ * 512 + sh_ * 256;            \
      _Pragma("unroll") for (int i_ = 0; i_ < 4; i_++) {                                  \
        int P_ = i_ * 512 + tid;                                                          \
        int row_ = P_ >> 4, u_ = P_ & 15;                                                 \
        int ul_ = u_ ^ (row_ & 7);                                                        \
        gload16(dst_ + (i_ * 512 + w * 64) * 16, srcb_ + (size_t)row_ * 512 + ul_ * 16);  \
      }                                                                                   \
    } else if (sp_ == 32) {                                                               \
      char* dst_ = smem + R_OFF(2);                                                       \
      _Pragma("unroll") for (int i_ = 0; i_ < 4; i_++) {                                  \
        int P_ = i_ * 512 + tid;                                                          \
        int row_ = P_ >> 3, u_ = P_ & 7;                                                  \
        int ul_ = u_ ^ (row_ & 7);                                                        \
        gload16(dst_ + (i_ * 512 + w * 64) * 16, (const char*)MmBg + row_ * 128 + ul_ * 16); \
      }                                                                                   \
    }                                                                                     \
    {                                                                                     \
      char* cur_ = smem + R_OFF(pp_ % 3);                                                 \
      const int brow_ = w * 16 + s;                                                       \
      const int bswz_ = brow_ & 7;                                                        \
      _Pragma("unroll") for (int kt4_ = 0; kt4_ < 4; kt4_++) {                            \
        bf16x8 bfrag_ =                                                                   \
            *(const bf16x8*)(cur_ + brow_ * 256 + (((kt4_ * 4 + g) ^ bswz_) * 16));       \
        _Pragma("unroll") for (int mf_ = 0; mf_ < 4; mf_++)                               \
            acc[mf_] = __builtin_amdgcn_mfma_f32_16x16x32_bf16(                           \
                a_cache[mf_][(H) * 4 + kt4_], bfrag_, acc[mf_], 0, 0, 0);                 \
      }                                                                                   \
    }                                                                                     \
  }

__global__ __launch_bounds__(512, 2) void fused_kernel(
    const bf16* __restrict__ Xt, const bf16* __restrict__ Wqb, const bf16* __restrict__ Wkb,
    const float* __restrict__ bq, const float* __restrict__ bk,
    const bf16* __restrict__ MmBg, const float* __restrict__ bo,
    const float* __restrict__ x, float* __restrict__ out) {
  __shared__ __align__(16) char smem[131072];
  const int tid = threadIdx.x;
  const int w = tid >> 6, lane = tid & 63;
  const int s = lane & 15, g = lane >> 4;
  const int pos0 = blockIdx.x * 64;

  // ---- prologue: biases -> LDS (plain load + ds_write) ----
  {
    float q0 = bq[tid], q1 = bq[tid + 512];
    float k0 = bk[tid], k1 = bk[tid + 512];
    *(float*)(smem + BQ_OFF + tid * 4) = q0;
    *(float*)(smem + BQ_OFF + (tid + 512) * 4) = q1;
    *(float*)(smem + BK_OFF + tid * 4) = k0;
    *(float*)(smem + BK_OFF + (tid + 512) * 4) = k1;
  }
  // ---- stage As (X tile, 64x256 bf16) -> R2, phase0 -> R0, phase1 -> R1 ----
  {
    const char* Xg = (const char*)Xt + (size_t)pos0 * 512;
#pragma unroll
    for (int i = 0; i < 4; i++) {
      int P = i * 512 + tid;
      int row = P >> 5, u = P & 31;
      int ul = u ^ (row & 7);
      gload16(smem + R_OFF(2) + (i * 512 + w * 64) * 16, Xg + (size_t)row * 512 + ul * 16);
    }
#pragma unroll
    for (int ph = 0; ph < 2; ph++) {
      char* dst = smem + R_OFF(ph);
      const char* srcb = (const char*)Wqb + ph * 256;  // chunk 0, half ph
#pragma unroll
      for (int i = 0; i < 4; i++) {
        int P = i * 512 + tid;
        int row = P >> 4, u = P & 15;
        int ul = u ^ (row & 7);
        gload16(dst + (i * 512 + w * 64) * 16, srcb + (size_t)row * 512 + ul * 16);
      }
    }
  }
  asm volatile("s_waitcnt vmcnt(0) lgkmcnt(0)" ::: "memory");
  __builtin_amdgcn_s_barrier();
  __builtin_amdgcn_sched_barrier(0);

  // ---- A fragments -> registers (held for whole kernel): 32 x bf16x8 ----
  bf16x8 a_cache[4][8];
#pragma unroll
  for (int mf = 0; mf < 4; mf++) {
    int arow = mf * 16 + s;
    int aswz = arow & 7;
#pragma unroll
    for (int kt = 0; kt < 8; kt++)
      a_cache[mf][kt] =
          *(const bf16x8*)(smem + R_OFF(2) + arow * 512 + (((kt * 4 + g) ^ aswz) * 16));
  }

  // ================= Q projection: 8 chunks x 128 outs =================
  float qacc[4][4] = {};
#pragma unroll
  for (int c = 0; c < 8; c++) {
    f32x4 acc[4] = {};
    PHASE(c * 2 + 0, 0);
    PHASE(c * 2 + 1, 1);
    float bqv = *(const float*)(smem + BQ_OFF + (c * 128 + w * 16 + s) * 4);
#pragma unroll
    for (int mf = 0; mf < 4; mf++)
#pragma unroll
      for (int r = 0; r < 4; r++) qacc[mf][r] += fmaxf(acc[mf][r] + bqv, 0.f);
  }

  // ---- merge qsum across 8 waves (via bf16 LDS), qreg = cscale * sum ----
#pragma unroll
  for (int mf = 0; mf < 4; mf++)
#pragma unroll
    for (int r = 0; r < 4; r++) {
      int pos_l = mf * 16 + g * 4 + r;
      *(bf16*)(smem + QSW_OFF + ((pos_l * 16 + s) * 8 + w) * 2) = __float2bfloat16(qacc[mf][r]);
    }
  asm volatile("s_waitcnt lgkmcnt(0)" ::: "memory");
  __builtin_amdgcn_s_barrier();
  __builtin_amdgcn_sched_barrier(0);
  float qreg[4][4];
#pragma unroll
  for (int mf = 0; mf < 4; mf++)
#pragma unroll
    for (int r = 0; r < 4; r++) {
      int pos_l = mf * 16 + g * 4 + r;
      bf16x8 vv = *(const bf16x8*)(smem + QSW_OFF + (pos_l * 16 + s) * 16);
      float sum = 0.f;
#pragma unroll
      for (int j = 0; j < 8; j++) sum += b2f(vv[j]);
      qreg[mf][r] = 0.00390625f * sum;  // (1/4)/64
    }

  // ================= K projection: 8 chunks, pooled via DPP s-reduce =================
#pragma unroll
  for (int c = 0; c < 8; c++) {
    f32x4 acc[4] = {};
    PHASE(16 + c * 2 + 0, 0);
    PHASE(16 + c * 2 + 1, 1);
    float bkv = *(const float*)(smem + BK_OFF + (c * 128 + w * 16 + s) * 4);
    float red[16];
#pragma unroll
    for (int mf = 0; mf < 4; mf++)
#pragma unroll
      for (int r = 0; r < 4; r++) {
        float t = qreg[mf][r] * fmaxf(acc[mf][r] + bkv, 0.f);
        t = dpp_add<0x128>(t);  // row_ror:8
        t = dpp_add<0x124>(t);  // row_ror:4
        t = dpp_add<0x122>(t);  // row_ror:2
        t = dpp_add<0x121>(t);  // row_ror:1
        red[mf * 4 + r] = t;    // full sum over 16 s-lanes, all lanes
      }
    // lane s takes red[s]; write pooledB[pos_l][n] (n = c*8+w), XOR-swizzled
    float a0 = (s & 1) ? red[1] : red[0];
    float a1 = (s & 1) ? red[3] : red[2];
    float a2 = (s & 1) ? red[5] : red[4];
    float a3 = (s & 1) ? red[7] : red[6];
    float a4 = (s & 1) ? red[9] : red[8];
    float a5 = (s & 1) ? red[11] : red[10];
    float a6 = (s & 1) ? red[13] : red[12];
    float a7 = (s & 1) ? red[15] : red[14];
    float b0 = (s & 2) ? a1 : a0;
    float b1 = (s & 2) ? a3 : a2;
    float b2 = (s & 2) ? a5 : a4;
    float b3 = (s & 2) ? a7 : a6;
    float c0 = (s & 4) ? b1 : b0;
    float c1 = (s & 4) ? b3 : b2;
    float val = (s & 8) ? c1 : c0;
    int pos_l = (s >> 2) * 16 + g * 4 + (s & 3);
    int n = c * 8 + w;
    *(bf16*)(smem + POOL_OFF + pos_l * 128 + ((n ^ ((pos_l & 7) << 3)) * 2)) =
        __float2bfloat16(val);
  }

  // ================= out = x + pooled @ MmB + bo =================
  asm volatile("s_waitcnt vmcnt(0) lgkmcnt(0)" ::: "memory");
  __builtin_amdgcn_s_barrier();
  __builtin_amdgcn_sched_barrier(0);
  {
    char* Mlds = smem + R_OFF(2);   // MmB [256 o2][64 n], swizzled
    char* Plds = smem + POOL_OFF;   // pooledB [64 pos][64 n], swizzled
    f32x4 oacc[2][4] = {};
#pragma unroll
    for (int kt = 0; kt < 2; kt++) {
      bf16x8 pf[4];
#pragma unroll
      for (int nfp = 0; nfp < 4; nfp++) {
        int prow = nfp * 16 + s;
        pf[nfp] = *(const bf16x8*)(Plds + prow * 128 + (((kt * 4 + g) ^ (prow & 7)) * 16));
      }
#pragma unroll
      for (int mfo = 0; mfo < 2; mfo++) {
        int mrow = w * 32 + mfo * 16 + s;
        bf16x8 mfr = *(const bf16x8*)(Mlds + mrow * 128 + (((kt * 4 + g) ^ (mrow & 7)) * 16));
#pragma unroll
        for (int nfp = 0; nfp < 4; nfp++)
          oacc[mfo][nfp] =
              __builtin_amdgcn_mfma_f32_16x16x32_bf16(mfr, pf[nfp], oacc[mfo][nfp], 0, 0, 0);
      }
    }
    int b = pos0 >> 12, l0 = pos0 & (LDIM - 1);
#pragma unroll
    for (int mfo = 0; mfo < 2; mfo++)
#pragma unroll
      for (int r = 0; r < 4; r++) {
        int o2 = w * 32 + mfo * 16 + g * 4 + r;
        float bov = bo[o2];
        const float* xr = x + ((size_t)(b * CDIM + o2) * LDIM) + l0;
        float* orow = out + ((size_t)(b * CDIM + o2) * LDIM) + l0;
#pragma unroll
        for (int nfp = 0; nfp < 4; nfp++) {
          int p = nfp * 16 + s;
          orow[p] = xr[p] + oacc[mfo][nfp][r] + bov;
        }
      }
  }
}

extern "C" void kernel_launch(void* const* d_in, const int* in_sizes, int n_in,
                              void* d_out, int out_size, void* d_ws, size_t ws_size,
                              hipStream_t stream) {
  (void)in_sizes; (void)n_in; (void)out_size; (void)ws_size;
  const float* x = (const float*)d_in[0];
  const float* Wq = (const float*)d_in[1];
  const float* bq = (const float*)d_in[2];
  const float* Wk = (const float*)d_in[3];
  const float* bk = (const float*)d_in[4];
  const float* v = (const float*)d_in[5];
  const float* Wo = (const float*)d_in[6];
  const float* bo = (const float*)d_in[7];
  float* out = (float*)d_out;

  char* ws = (char*)d_ws;
  bf16* Xt = (bf16*)ws;                      // 8,388,608
  bf16* Wqb = (bf16*)(ws + 8388608);         // 524,288
  bf16* Wkb = (bf16*)(ws + 8912896);         // 524,288
  bf16* MmBg = (bf16*)(ws + 9437184);        // 32,768  (end 9,469,952)

  prep_kernel<<<768, 256, 0, stream>>>(Wq, Wk, v, Wo, Wqb, Wkb, MmBg);
  transpose_cast_kernel<<<dim3(64, 4, 4), 256, 0, stream>>>(x, Xt);
  fused_kernel<<<256, 512, 0, stream>>>(Xt, Wqb, Wkb, bq, bk, MmBg, bo, x, out);
}